// Round 8
// baseline (251.828 us; speedup 1.0000x reference)
//
#include <hip/hip_runtime.h>
#include <math.h>

#define N_NODES 16384
#define N_EDGES 262144
#define IN_DIM  512
#define HID     256
#define HEADS   4
#define NBATCH  64
#define ACTIONS 32
#define NEG_SLOPE 0.2f

typedef __attribute__((ext_vector_type(8))) short short8;
typedef __attribute__((ext_vector_type(4))) float f32x4;

__device__ __forceinline__ float lrelu(float v) { return v > 0.f ? v : NEG_SLOPE * v; }

__device__ __forceinline__ unsigned short bf16_rne(float f) {
    union { float f; unsigned int u; } x; x.f = f;
    unsigned int u = x.u;
    unsigned int r = (u + 0x7FFFu + ((u >> 16) & 1u)) >> 16;
    return (unsigned short)r;
}

__device__ __forceinline__ float bf16_to_f32(unsigned short s) {
    union { unsigned int u; float f; } x; x.u = (unsigned int)s << 16;
    return x.f;
}

__device__ __forceinline__ float bfe(short8 v, int j) {
    return bf16_to_f32((unsigned short)v[j]);
}

__device__ __forceinline__ void async_copy16(const unsigned short* g, unsigned short* l) {
    __builtin_amdgcn_global_load_lds(
        (const __attribute__((address_space(1))) unsigned int*)g,
        (__attribute__((address_space(3))) unsigned int*)l, 16, 0, 0);
}

// ---------------------------------------------------------------- fused setup (+ deg count + x->bf16 convert)
#define NB_WLR   1024
#define NB_WSTK  1024
#define NB_WATT  512    // 2048 wave-tasks (8 j x 256 c), 4 waves/block
#define NB_DEG   1024
#define NB_XCONV 4096   // N*IN_DIM / (256*8)
#define NB_SETUP (NB_WLR + NB_WSTK + NB_WATT + NB_DEG + NB_XCONV)

__global__ __launch_bounds__(256) void setup_kernel(
        const float* __restrict__ wl, const float* __restrict__ wr, unsigned short* __restrict__ bt1,
        const float* __restrict__ gat_w, unsigned short* __restrict__ bt2,
        const float* __restrict__ att_src, const float* __restrict__ att_dst, float* __restrict__ watt,
        const int* __restrict__ ei, int* __restrict__ deg,
        const float* __restrict__ x, unsigned short* __restrict__ xb) {
    int bid = blockIdx.x, tid = threadIdx.x;
    if (bid < NB_WLR) {
        int idx = bid * 256 + tid;
        int j = idx >> 9;
        int k = idx & 511;
        float v = (j < HID) ? wl[k * HID + j] : wr[k * HID + (j - HID)];
        bt1[idx] = bf16_rne(v);
    } else if (bid < NB_WLR + NB_WSTK) {
        int idx = (bid - NB_WLR) * 256 + tid;
        int c = idx >> 10;
        int r = idx & 1023;
        int h = r >> 8;
        int k = r & 255;
        bt2[idx] = bf16_rne(gat_w[(size_t)k * (HEADS * HID) + h * HID + c]);
    } else if (bid < NB_WLR + NB_WSTK + NB_WATT) {
        int t    = (bid - NB_WLR - NB_WSTK) * 4 + (tid >> 6);  // wave task 0..2047
        int lane = tid & 63;
        int j = t >> 8;          // 0..7
        int c = t & 255;
        int hh = j & 3;
        const float* att = (j < 4) ? (att_src + hh * HID) : (att_dst + hh * HID);
        float s = 0.f;
#pragma unroll
        for (int it = 0; it < 4; it++) {
            int cc = lane + it * 64;
            s += gat_w[(size_t)c * (HEADS * HID) + hh * HID + cc] * att[cc];
        }
#pragma unroll
        for (int off = 32; off; off >>= 1) s += __shfl_down(s, off);
        if (lane == 0) watt[j * HID + c] = s;
    } else if (bid < NB_WLR + NB_WSTK + NB_WATT + NB_DEG) {
        int e = (bid - NB_WLR - NB_WSTK - NB_WATT) * 256 + tid;
        if (e < N_EDGES) atomicAdd(&deg[ei[N_EDGES + e]], 1);
    } else {
        size_t idx = (size_t)(bid - NB_WLR - NB_WSTK - NB_WATT - NB_DEG) * 2048 + (size_t)tid * 8;
        float4 a0 = *(const float4*)(x + idx);
        float4 a1 = *(const float4*)(x + idx + 4);
        short8 p;
        p[0] = (short)bf16_rne(a0.x); p[1] = (short)bf16_rne(a0.y);
        p[2] = (short)bf16_rne(a0.z); p[3] = (short)bf16_rne(a0.w);
        p[4] = (short)bf16_rne(a1.x); p[5] = (short)bf16_rne(a1.y);
        p[6] = (short)bf16_rne(a1.z); p[7] = (short)bf16_rne(a1.w);
        *(short8*)(xb + idx) = p;
    }
}

// ---------------------------------------------------------------- CSR scan
__global__ __launch_bounds__(256) void scan_kernel(const int* __restrict__ deg,
                                                   int* __restrict__ row_start,
                                                   int* __restrict__ pos) {
    int t = threadIdx.x;
    int lane = t & 63, wv = t >> 6;
    int base = t * 64;
    int4 buf[16];
    int sum = 0;
#pragma unroll
    for (int i = 0; i < 16; i++) {
        buf[i] = ((const int4*)(deg + base))[i];
        sum += buf[i].x + buf[i].y + buf[i].z + buf[i].w;
    }
    int v = sum;
#pragma unroll
    for (int off = 1; off < 64; off <<= 1) {
        int u = __shfl_up(v, off);
        if (lane >= off) v += u;
    }
    __shared__ int wsum[4];
    if (lane == 63) wsum[wv] = v;
    __syncthreads();
    int wbase = 0;
    for (int w0 = 0; w0 < wv; w0++) wbase += wsum[w0];
    int run = wbase + v - sum;
#pragma unroll
    for (int i = 0; i < 16; i++) {
        int4 b = buf[i];
        int4 o;
        o.x = run; run += b.x;
        o.y = run; run += b.y;
        o.z = run; run += b.z;
        o.w = run; run += b.w;
        ((int4*)(row_start + base))[i] = o;
        ((int4*)(pos + base))[i] = o;
    }
    if (t == 255) row_start[N_NODES] = run;
}

// ---------------------------------------------------------------- CSR fill
__global__ void fill_kernel(const int* __restrict__ ei, int* __restrict__ pos,
                            int* __restrict__ col) {
    int e = blockIdx.x * 256 + threadIdx.x;
    if (e < N_EDGES) {
        int s = ei[e];
        int d = ei[N_EDGES + e];
        int p = atomicAdd(&pos[d], 1);
        col[p] = s;
    }
}

// ---------------------------------------------------------------- GEMM1: 128x128 tile, single-buffer, all-async, XCD-swizzled
#define BK 32

__global__ __launch_bounds__(256) void gemm1_kernel(const unsigned short* __restrict__ Ab,
                                                    const unsigned short* __restrict__ Bt,
                                                    unsigned short* __restrict__ Cb,
                                                    int Nn, int K) {
    __shared__ __align__(16) unsigned short As[128 * BK];
    __shared__ __align__(16) unsigned short Bs[128 * BK];

    int tid  = threadIdx.x;
    int wv   = tid >> 6;
    int lane = tid & 63;

    int L  = blockIdx.y * 4 + blockIdx.x;
    int nt = (L >> 3) & 3;
    int mt = (L & 7) * 16 + (L >> 5);
    int m0 = mt * 128;
    int n0 = nt * 128;
    int wr = (wv & 1) * 64;
    int wc = (wv >> 1) * 64;

    int srow = tid >> 2;            // 0..63
    int scol = (tid & 3) * 8;       // 0,8,16,24
    const unsigned short* Ag0 = Ab + (size_t)(m0 + srow) * K + scol;
    const unsigned short* Ag1 = Ag0 + (size_t)64 * K;
    const unsigned short* Bg0 = Bt + (size_t)(n0 + srow) * K + scol;
    const unsigned short* Bg1 = Bg0 + (size_t)64 * K;

    int fr = lane & 15;
    int fk = (lane >> 4) * 8;
    f32x4 acc[4][4] = {};

    for (int kt = 0; kt < K; kt += BK) {
        async_copy16(Ag0 + kt, &As[wv * 512]);
        async_copy16(Ag1 + kt, &As[2048 + wv * 512]);
        async_copy16(Bg0 + kt, &Bs[wv * 512]);
        async_copy16(Bg1 + kt, &Bs[2048 + wv * 512]);
        __syncthreads();

        short8 af[4], bf[4];
#pragma unroll
        for (int mi = 0; mi < 4; mi++)
            af[mi] = *(const short8*)&As[(wr + mi * 16 + fr) * BK + fk];
#pragma unroll
        for (int ni = 0; ni < 4; ni++)
            bf[ni] = *(const short8*)&Bs[(wc + ni * 16 + fr) * BK + fk];
#pragma unroll
        for (int mi = 0; mi < 4; mi++)
#pragma unroll
            for (int ni = 0; ni < 4; ni++)
                acc[mi][ni] = __builtin_amdgcn_mfma_f32_16x16x32_bf16(af[mi], bf[ni], acc[mi][ni], 0, 0, 0);
        __syncthreads();
    }

    int cr = (lane >> 4) * 4;
    int cc = lane & 15;
#pragma unroll
    for (int mi = 0; mi < 4; mi++) {
#pragma unroll
        for (int ni = 0; ni < 4; ni++) {
            int gc = n0 + wc + ni * 16 + cc;
#pragma unroll
            for (int r = 0; r < 4; r++) {
                int gr = m0 + wr + mi * 16 + cr + r;
                Cb[(size_t)gr * Nn + gc] = bf16_rne(acc[mi][ni][r]);
            }
        }
    }
}

// ---------------------------------------------------------------- GEMM2: 64x128, XCD-swizzled, fused pool (R5-proven)
__global__ __launch_bounds__(256) void gemm2_pool_kernel(const unsigned short* __restrict__ A,
                                                         const unsigned short* __restrict__ Bt,
                                                         const int* __restrict__ batch,
                                                         const float* __restrict__ bias,
                                                         float scale,
                                                         float* __restrict__ pooled,
                                                         int Nn, int K) {
    __shared__ __align__(16) unsigned short As[2][2][64 * BK];
    __shared__ __align__(16) unsigned short Bs[2][2][128 * BK];
    __shared__ int bsh[64];

    int tid  = threadIdx.x;
    int wv   = tid >> 6;
    int lane = tid & 63;

    int L = blockIdx.y * 2 + blockIdx.x;
    int mt = (L & 7) + (L >> 4) * 8;   // 0..255
    int nt = (L >> 3) & 1;             // 0..1
    int m0 = mt * 64;
    int n0 = nt * 128;
    int wm = (wv & 1) * 32;
    int wn = (wv >> 1) * 64;

    if (tid < 64) bsh[tid] = batch[m0 + tid];

    int srow = tid >> 2;
    int scol = (tid & 3) * 8;
    const unsigned short* Ag  = A  + (size_t)(m0 + srow) * K + scol;
    const unsigned short* Bg0 = Bt + (size_t)(n0 + srow) * K + scol;
    const unsigned short* Bg1 = Bt + (size_t)(n0 + 64 + srow) * K + scol;

    int fr = lane & 15;
    int fk = (lane >> 4) * 8;
    f32x4 acc[2][4] = {};

#pragma unroll
    for (int s = 0; s < 2; s++) {
        int ko = s * BK;
        async_copy16(Ag + ko,  &As[0][s][wv * 512]);
        async_copy16(Bg0 + ko, &Bs[0][s][wv * 512]);
        async_copy16(Bg1 + ko, &Bs[0][s][2048 + wv * 512]);
    }
    __syncthreads();

    int cur = 0;
    for (int kt = 0; kt < K; kt += 2 * BK) {
        int nxt = kt + 2 * BK;
        bool pf = nxt < K;
        if (pf) {
#pragma unroll
            for (int s = 0; s < 2; s++) {
                int ko = nxt + s * BK;
                async_copy16(Ag + ko,  &As[cur ^ 1][s][wv * 512]);
                async_copy16(Bg0 + ko, &Bs[cur ^ 1][s][wv * 512]);
                async_copy16(Bg1 + ko, &Bs[cur ^ 1][s][2048 + wv * 512]);
            }
        }

#pragma unroll
        for (int s = 0; s < 2; s++) {
            short8 af[2], bf[4];
#pragma unroll
            for (int mi = 0; mi < 2; mi++)
                af[mi] = *(const short8*)&As[cur][s][(wm + mi * 16 + fr) * BK + fk];
#pragma unroll
            for (int ni = 0; ni < 4; ni++)
                bf[ni] = *(const short8*)&Bs[cur][s][(wn + ni * 16 + fr) * BK + fk];
#pragma unroll
            for (int mi = 0; mi < 2; mi++)
#pragma unroll
                for (int ni = 0; ni < 4; ni++)
                    acc[mi][ni] = __builtin_amdgcn_mfma_f32_16x16x32_bf16(af[mi], bf[ni], acc[mi][ni], 0, 0, 0);
        }
        __syncthreads();
        cur ^= 1;
    }

    int cr = (lane >> 4) * 4;
    int cc = lane & 15;
#pragma unroll
    for (int mi = 0; mi < 2; mi++) {
        int rowb = wm + mi * 16 + cr;
        int b0 = bsh[rowb], b3 = bsh[rowb + 3];
#pragma unroll
        for (int ni = 0; ni < 4; ni++) {
            int gc = n0 + wn + ni * 16 + cc;
            float b = bias[gc];
            float v0 = fmaxf(fmaf(acc[mi][ni][0], scale, b), 0.f);
            float v1 = fmaxf(fmaf(acc[mi][ni][1], scale, b), 0.f);
            float v2 = fmaxf(fmaf(acc[mi][ni][2], scale, b), 0.f);
            float v3 = fmaxf(fmaf(acc[mi][ni][3], scale, b), 0.f);
            if (b0 == b3) {
                atomicAdd(&pooled[b0 * HID + gc], (v0 + v1) + (v2 + v3));
            } else {
                atomicAdd(&pooled[bsh[rowb + 0] * HID + gc], v0);
                atomicAdd(&pooled[bsh[rowb + 1] * HID + gc], v1);
                atomicAdd(&pooled[bsh[rowb + 2] * HID + gc], v2);
                atomicAdd(&pooled[bsh[rowb + 3] * HID + gc], v3);
            }
        }
    }
}

// ---------------------------------------------------------------- SAGE aggregation: paired-row gather (2 edges / wave-instr,
// 16B/lane). Lanes 0-31 handle edge e, lanes 32-63 edge e+1; per-lane 8 cols; halves merged by shfl_xor(32).
__global__ __launch_bounds__(256) void sage_agg_kernel(const unsigned short* __restrict__ xlr,
                                                       const int* __restrict__ row_start,
                                                       const int* __restrict__ col,
                                                       const float* __restrict__ b_l,
                                                       const float* __restrict__ watt,
                                                       unsigned short* __restrict__ hb,
                                                       float* __restrict__ a_att) {
    __shared__ __align__(16) float watt_s[8 * HID];
    for (int i = threadIdx.x; i < 8 * HID; i += 256) watt_s[i] = watt[i];
    __syncthreads();

    int wave = threadIdx.x >> 6;
    int lane = threadIdx.x & 63;
    int lh   = lane >> 5;        // half: 0 or 1
    int cb   = (lane & 31) * 8;  // 8 cols per lane
    int n = blockIdx.x * 4 + wave;
    int start = row_start[n], end = row_start[n + 1];

    const unsigned short* xg = xlr + cb;
    float a[8] = {0.f, 0.f, 0.f, 0.f, 0.f, 0.f, 0.f, 0.f};

    int e = start;
    for (; e + 4 <= end; e += 4) {
        int s0 = col[e + lh];
        int s1 = col[e + 2 + lh];
        short8 u0 = *(const short8*)(xg + (size_t)s0 * IN_DIM);
        short8 u1 = *(const short8*)(xg + (size_t)s1 * IN_DIM);
#pragma unroll
        for (int j = 0; j < 8; j++) a[j] += bfe(u0, j) + bfe(u1, j);
    }
    for (; e + 2 <= end; e += 2) {
        int s0 = col[e + lh];
        short8 u0 = *(const short8*)(xg + (size_t)s0 * IN_DIM);
#pragma unroll
        for (int j = 0; j < 8; j++) a[j] += bfe(u0, j);
    }
    if (e < end) {
        int s0 = col[e];
        short8 u0 = *(const short8*)(xg + (size_t)s0 * IN_DIM);
        if (lh == 0) {
#pragma unroll
            for (int j = 0; j < 8; j++) a[j] += bfe(u0, j);
        }
    }
    // merge the two half-wave partial sums (both halves end with the full sum)
#pragma unroll
    for (int j = 0; j < 8; j++) a[j] += __shfl_xor(a[j], 32);

    float inv = 1.f / (float)max(end - start, 1);
    short8 ur = *(const short8*)(xlr + (size_t)n * IN_DIM + HID + cb);
    float4 bl0 = *(const float4*)(b_l + cb);
    float4 bl1 = *(const float4*)(b_l + cb + 4);
    float blv[8] = {bl0.x, bl0.y, bl0.z, bl0.w, bl1.x, bl1.y, bl1.z, bl1.w};
    float hv[8];
#pragma unroll
    for (int j = 0; j < 8; j++)
        hv[j] = fmaxf(fmaf(a[j], inv, blv[j] + bfe(ur, j)), 0.f);

    if (lh == 0) {
        short8 ho;
#pragma unroll
        for (int j = 0; j < 8; j++) ho[j] = (short)bf16_rne(hv[j]);
        *(short8*)(hb + (size_t)n * HID + cb) = ho;
    }

    // attention logits: each col appears in exactly 2 lanes (l, l^32) -> scale by 0.5 at the end
    float p[8];
#pragma unroll
    for (int jj = 0; jj < 8; jj++) {
        float4 w0 = *(const float4*)&watt_s[jj * HID + cb];
        float4 w1 = *(const float4*)&watt_s[jj * HID + cb + 4];
        p[jj] = hv[0] * w0.x + hv[1] * w0.y + hv[2] * w0.z + hv[3] * w0.w
              + hv[4] * w1.x + hv[5] * w1.y + hv[6] * w1.z + hv[7] * w1.w;
    }
#pragma unroll
    for (int off = 32; off; off >>= 1)
#pragma unroll
        for (int jj = 0; jj < 8; jj++) p[jj] += __shfl_down(p[jj], off);
    if (lane == 0) {
#pragma unroll
        for (int jj = 0; jj < 8; jj++) a_att[n * 8 + jj] = p[jj] * 0.5f;
    }
}

// ---------------------------------------------------------------- GAT: paired-row gather softmax+aggregation
__global__ __launch_bounds__(256) void gat_agg_kernel(const unsigned short* __restrict__ hb,
                                                      const float* __restrict__ a_att,
                                                      const int* __restrict__ row_start,
                                                      const int* __restrict__ col,
                                                      unsigned short* __restrict__ T) {
    __shared__ __align__(16) float w_s[4][64 * 4];
    int wave = threadIdx.x >> 6;
    int lane = threadIdx.x & 63;
    int lh   = lane >> 5;
    int cb   = (lane & 31) * 8;
    int n = blockIdx.x * 4 + wave;
    int start = row_start[n], end = row_start[n + 1];

    float4 an = *(const float4*)(a_att + n * 8);
    float4 ad = *(const float4*)(a_att + n * 8 + 4);
    float adst[4] = {ad.x, ad.y, ad.z, ad.w};
    float selfl[4] = {lrelu(an.x + ad.x), lrelu(an.y + ad.y), lrelu(an.z + ad.z), lrelu(an.w + ad.w)};
    float m[4], wself[4];
#pragma unroll
    for (int hh = 0; hh < 4; hh++) {
        m[hh] = fmaxf(selfl[hh], 0.f);
        wself[hh] = __expf(selfl[hh] - m[hh]);
    }

    const unsigned short* hg = hb + cb;
    // self term: only lh==0 lanes seed it (xor-merge would double it otherwise)
    short8 un = *(const short8*)(hg + (size_t)n * HID);
    float acc[4][8];
#pragma unroll
    for (int hh = 0; hh < 4; hh++) {
        float w0 = (lh == 0) ? wself[hh] : 0.f;
#pragma unroll
        for (int j = 0; j < 8; j++) acc[hh][j] = w0 * bfe(un, j);
    }

    float dpart[4] = {0.f, 0.f, 0.f, 0.f};

    for (int base = start; base < end; base += 64) {
        int cnt = min(64, end - base);
        if (lane < cnt) {
            int s = col[base + lane];
            float4 as = *(const float4*)(a_att + s * 8);
            float4 wv;
            wv.x = __expf(lrelu(as.x + adst[0]) - m[0]);
            wv.y = __expf(lrelu(as.y + adst[1]) - m[1]);
            wv.z = __expf(lrelu(as.z + adst[2]) - m[2]);
            wv.w = __expf(lrelu(as.w + adst[3]) - m[3]);
            *(float4*)&w_s[wave][lane * 4] = wv;
            dpart[0] += wv.x; dpart[1] += wv.y; dpart[2] += wv.z; dpart[3] += wv.w;
        }
        __builtin_amdgcn_wave_barrier();

        int i = 0;
        for (; i + 4 <= cnt; i += 4) {
            int s0 = col[base + i + lh];
            int s1 = col[base + i + 2 + lh];
            float4 w0 = *(const float4*)&w_s[wave][(i + lh) * 4];
            float4 w1 = *(const float4*)&w_s[wave][(i + 2 + lh) * 4];
            short8 u0 = *(const short8*)(hg + (size_t)s0 * HID);
            short8 u1 = *(const short8*)(hg + (size_t)s1 * HID);
            float wr0[4] = {w0.x, w0.y, w0.z, w0.w};
            float wr1[4] = {w1.x, w1.y, w1.z, w1.w};
#pragma unroll
            for (int hh = 0; hh < 4; hh++)
#pragma unroll
                for (int j = 0; j < 8; j++)
                    acc[hh][j] = fmaf(wr0[hh], bfe(u0, j), fmaf(wr1[hh], bfe(u1, j), acc[hh][j]));
        }
        for (; i + 2 <= cnt; i += 2) {
            int s0 = col[base + i + lh];
            float4 w0 = *(const float4*)&w_s[wave][(i + lh) * 4];
            short8 u0 = *(const short8*)(hg + (size_t)s0 * HID);
            float wr0[4] = {w0.x, w0.y, w0.z, w0.w};
#pragma unroll
            for (int hh = 0; hh < 4; hh++)
#pragma unroll
                for (int j = 0; j < 8; j++)
                    acc[hh][j] = fmaf(wr0[hh], bfe(u0, j), acc[hh][j]);
        }
        if (i < cnt) {
            int s0 = col[base + i];
            float4 w0 = *(const float4*)&w_s[wave][i * 4];
            short8 u0 = *(const short8*)(hg + (size_t)s0 * HID);
            if (lh == 0) {
                float wr0[4] = {w0.x, w0.y, w0.z, w0.w};
#pragma unroll
                for (int hh = 0; hh < 4; hh++)
#pragma unroll
                    for (int j = 0; j < 8; j++)
                        acc[hh][j] = fmaf(wr0[hh], bfe(u0, j), acc[hh][j]);
            }
        }
        __builtin_amdgcn_wave_barrier();
    }

    // merge half-wave partials
#pragma unroll
    for (int hh = 0; hh < 4; hh++)
#pragma unroll
        for (int j = 0; j < 8; j++) acc[hh][j] += __shfl_xor(acc[hh][j], 32);

#pragma unroll
    for (int off = 32; off; off >>= 1)
#pragma unroll
        for (int hh = 0; hh < 4; hh++) dpart[hh] += __shfl_down(dpart[hh], off);
    float invd[4];
#pragma unroll
    for (int hh = 0; hh < 4; hh++)
        invd[hh] = 1.f / (__shfl(dpart[hh], 0) + wself[hh]);

    if (lh == 0) {
#pragma unroll
        for (int hh = 0; hh < 4; hh++) {
            short8 o;
#pragma unroll
            for (int j = 0; j < 8; j++) o[j] = (short)bf16_rne(acc[hh][j] * invd[hh]);
            *(short8*)(T + (size_t)n * (HEADS * HID) + hh * HID + cb) = o;
        }
    }
}

// ---------------------------------------------------------------- head
__device__ __forceinline__ int lower_bound_i(const int* a, int n, int v) {
    int lo = 0, hi = n;
    while (lo < hi) {
        int mid = (lo + hi) >> 1;
        if (a[mid] < v) lo = mid + 1; else hi = mid;
    }
    return lo;
}

__global__ __launch_bounds__(256) void head_kernel(const float* __restrict__ pooled,
                                                   const int* __restrict__ batch,
                                                   const float* __restrict__ head_w,
                                                   const float* __restrict__ head_b,
                                                   float* __restrict__ out) {
    __shared__ float sm[HID];
    int b = blockIdx.x;
    int c = threadIdx.x;
    int lo = lower_bound_i(batch, N_NODES, b);
    int hi = lower_bound_i(batch, N_NODES, b + 1);
    int cnt = hi - lo;
    sm[c] = pooled[b * HID + c] / (float)max(cnt, 1);
    __syncthreads();
    if (c < ACTIONS) {
        float acc = head_b[c];
        for (int k = 0; k < HID; k++) acc = fmaf(sm[k], head_w[k * ACTIONS + c], acc);
        out[b * ACTIONS + c] = acc;
    }
}

// ---------------------------------------------------------------- launcher
extern "C" void kernel_launch(void* const* d_in, const int* in_sizes, int n_in,
                              void* d_out, int out_size, void* d_ws, size_t ws_size,
                              hipStream_t stream) {
    const float* x        = (const float*)d_in[0];
    const int*   ei       = (const int*)d_in[1];
    const int*   batch    = (const int*)d_in[2];
    const float* sage_w_l = (const float*)d_in[3];
    const float* sage_b_l = (const float*)d_in[4];
    const float* sage_w_r = (const float*)d_in[5];
    const float* gat_w    = (const float*)d_in[6];
    const float* att_src  = (const float*)d_in[7];
    const float* att_dst  = (const float*)d_in[8];
    const float* gat_b    = (const float*)d_in[9];
    const float* head_w   = (const float*)d_in[10];
    const float* head_b   = (const float*)d_in[11];
    float* out = (float*)d_out;

    char* w = (char*)d_ws;
    // --- zeroed region (single memset): deg | pooled ---
    int*   deg     = (int*)w;   w += (size_t)N_NODES * 4;           // 64 KB
    float* pooled  = (float*)w; w += (size_t)NBATCH * HID * 4;      // 64 KB
    size_t zero_bytes = (size_t)N_NODES * 4 + (size_t)NBATCH * HID * 4;
    // --- rest ---
    float* a_att  = (float*)w; w += (size_t)N_NODES * 8 * 4;
    float* watt   = (float*)w; w += (size_t)8 * HID * 4;
    unsigned short* xlr = (unsigned short*)w; w += (size_t)N_NODES * IN_DIM * 2;
    unsigned short* hb  = (unsigned short*)w; w += (size_t)N_NODES * HID * 2;
    unsigned short* T   = (unsigned short*)w; w += (size_t)N_NODES * HEADS * HID * 2;
    unsigned short* bt1 = (unsigned short*)w; w += (size_t)(2 * HID) * IN_DIM * 2;
    unsigned short* bt2 = (unsigned short*)w; w += (size_t)HID * (HEADS * HID) * 2;
    int* row_start= (int*)w;   w += (size_t)(N_NODES + 64) * 4;
    int* pos      = (int*)w;   w += (size_t)N_NODES * 4;
    int* col      = (int*)w;   w += (size_t)N_EDGES * 4;

    // xb (bf16 copy of x, 16 MB) aliases T (32 MB): xb is dead before gat_agg writes T.
    unsigned short* xb = T;

    hipMemsetAsync(d_ws, 0, zero_bytes, stream);

    setup_kernel<<<NB_SETUP, 256, 0, stream>>>(sage_w_l, sage_w_r, bt1,
                                               gat_w, bt2, att_src, att_dst, watt,
                                               ei, deg, x, xb);

    scan_kernel<<<1, 256, 0, stream>>>(deg, row_start, pos);
    fill_kernel<<<N_EDGES / 256, 256, 0, stream>>>(ei, pos, col);

    // xlr = xb @ [W_l | W_r]
    gemm1_kernel<<<dim3(4, N_NODES / 128), 256, 0, stream>>>(
        xb, bt1, xlr, 2 * HID, IN_DIM);

    sage_agg_kernel<<<N_NODES / 4, 256, 0, stream>>>(xlr, row_start, col, sage_b_l, watt, hb, a_att);

    gat_agg_kernel<<<N_NODES / 4, 256, 0, stream>>>(hb, a_att, row_start, col, T);

    gemm2_pool_kernel<<<dim3(2, N_NODES / 64), 256, 0, stream>>>(
        T, bt2, batch, gat_b, 0.25f, pooled, HID, HEADS * HID);

    head_kernel<<<NBATCH, 256, 0, stream>>>(pooled, batch, head_w, head_b, out);
}